// Round 8
// baseline (87.525 us; speedup 1.0000x reference)
//
#include <hip/hip_runtime.h>
#include <stdint.h>

// Problem constants (B=1, L=256, C=128, N=4, TN=4)
#define LLTOT 65536
#define CDIM  128
#define TPIX  32

typedef float f32x4 __attribute__((ext_vector_type(4)));
typedef short s16x8 __attribute__((ext_vector_type(8)));

#define MFMA16(a, b, c) __builtin_amdgcn_mfma_f32_16x16x32_bf16((a), (b), (c), 0, 0, 0)

// ---- persistent device scratch (weights only) ----
// fragment-linear layouts: [tile][kk][lane 0..63][8 bf16]  (lane: row = l&15, k-chunk = l>>4)
__device__ __align__(16) unsigned short g_wefff[2 * 4 * 64 * 8];    // routing weights (rows 24-31 zero)
__device__ __align__(16) unsigned short g_w1gf[32 * 4 * 64 * 8];    // W1 * ln_g
__device__ __align__(16) unsigned short g_w2f [8 * 16 * 64 * 8];    // W2
__device__ __align__(16) float  g_hA[512];                          // b1 + W1 @ ln_b
__device__ __align__(16) float  g_w1gs[512];                        // row sums of W1*ln_g

__device__ __forceinline__ unsigned short f2bf(float f) {
    union { float f; uint32_t u; } v; v.f = f;
    uint32_t u = v.u;
    return (unsigned short)((u + 0x7FFFu + ((u >> 16) & 1u)) >> 16);
}
__device__ __forceinline__ uint32_t pack2(float a, float b) {
    return (uint32_t)f2bf(a) | ((uint32_t)f2bf(b) << 16);
}
__device__ __forceinline__ float bf2f(uint32_t lo16) { return __uint_as_float(lo16 << 16); }

__device__ __forceinline__ float fast_tanh(float x) {
    float cx = fminf(fmaxf(x, -10.f), 10.f);
    float e = __expf(2.f * cx);
    return (e - 1.f) * __builtin_amdgcn_rcpf(e + 1.f);
}
__device__ __forceinline__ float fast_sig(float z) {
    return __builtin_amdgcn_rcpf(1.f + __expf(-z));
}

// ---- prep: fold weights, convert to bf16, write fragment-linear layouts ----
__global__ void prep_kernel(const float* __restrict__ Wpre, const float* __restrict__ Wpost,
                            const float* __restrict__ Wres, const float* __restrict__ W1,
                            const float* __restrict__ W2, const float* __restrict__ ln_g,
                            const float* __restrict__ ln_b, const float* __restrict__ b1) {
    int b = blockIdx.x, t = threadIdx.x;
    if (b == 264) {
        int j = t;   // 512 threads
        float sg = 0.f, sb = 0.f;
        const float* row = W1 + j * 128;
        #pragma unroll 4
        for (int c = 0; c < 128; c += 4) {
            float4 wv = *(const float4*)(row + c);
            float4 gv = *(const float4*)(ln_g + c);
            float4 bv = *(const float4*)(ln_b + c);
            sg += wv.x*gv.x + wv.y*gv.y + wv.z*gv.z + wv.w*gv.w;
            sb += wv.x*bv.x + wv.y*bv.y + wv.z*bv.z + wv.w*bv.w;
        }
        g_hA[j]   = b1[j] + sb;
        g_w1gs[j] = sg;
        return;
    }
    int idx = b * 512 + t;
    if (idx < 4096) {
        // weff fragments: d -> (tile,kk,lane,e)
        int e = idx & 7, lane = (idx >> 3) & 63, kk = (idx >> 9) & 3, tile = idx >> 11;
        int o = tile * 16 + (lane & 15);
        int c = kk * 32 + (lane >> 4) * 8 + e;
        float v = 0.f;
        if (o < 4)        v = Wpre[o*512+c] + Wpre[o*512+128+c] + Wpre[o*512+256+c] + Wpre[o*512+384+c];
        else if (o < 8)   { int j = o - 4;  v = Wpost[j*512+c] + Wpost[j*512+128+c] + Wpost[j*512+256+c] + Wpost[j*512+384+c]; }
        else if (o < 24)  { int j = o - 8;  v = Wres[j*512+c] + Wres[j*512+128+c] + Wres[j*512+256+c] + Wres[j*512+384+c]; }
        g_wefff[idx] = f2bf(v);
    } else if (idx < 69632) {
        int d = idx - 4096;
        int e = d & 7, lane = (d >> 3) & 63, kk = (d >> 9) & 3, jt = d >> 11;
        int j = jt * 16 + (lane & 15);
        int c = kk * 32 + (lane >> 4) * 8 + e;
        g_w1gf[d] = f2bf(W1[j * 128 + c] * ln_g[c]);
    } else if (idx < 135168) {
        int d = idx - 69632;
        int e = d & 7, lane = (d >> 3) & 63, kk = (d >> 9) & 15, ct = d >> 13;
        int c = ct * 16 + (lane & 15);
        int k = kk * 32 + (lane >> 4) * 8 + e;
        g_w2f[d] = f2bf(W2[c * 512 + k]);
    }
}

// ---- fused: waves 0-1 route ; 2-phase MLP (16 KB h) ; 4 barriers ----
__global__ void __launch_bounds__(512, 8) fused_kernel(
    const float* __restrict__ p, const float* __restrict__ p_mask,
    const float* __restrict__ b_pre, const float* __restrict__ b_post, const float* __restrict__ b_res,
    const float* __restrict__ a_pre, const float* __restrict__ a_post, const float* __restrict__ a_res,
    const float* __restrict__ b2g, float* __restrict__ out)
{
    __shared__ __align__(16) unsigned short pf_lds[8 * 64 * 8];   // 8 KB bf16 p fragments
    __shared__ __align__(16) unsigned short h_s[TPIX * 256];      // 16 KB bf16 relu(h) HALF, row stride 512B, swz <<5
    __shared__ __align__(16) float A_s[TPIX * 4], B_s[TPIX * 4];  // 1 KB
    __shared__ __align__(16) float2 simi_s[TPIX];                 // 256 B

    const int t = threadIdx.x;
    const int w = t >> 6, l = t & 63, lr = l & 15, lk = l >> 4;
    const size_t base = (size_t)blockIdx.x * 32;

    // ======== waves 0-1: full route for this block's 32 pixels (no barriers inside) ========
    if (w < 2) {
        const int g = lk, pixl = lr;
        const size_t gpix = base + w * 16 + pixl;

        float s = 0.f, ss = 0.f;
        s16x8 pf[4];
        const float* prow = p + gpix * 128 + g * 8;
        #pragma unroll
        for (int kk = 0; kk < 4; ++kk) {
            float4 va = *(const float4*)(prow + kk * 32);
            float4 vb = *(const float4*)(prow + kk * 32 + 4);
            s  += va.x + va.y + va.z + va.w + vb.x + vb.y + vb.z + vb.w;
            ss += va.x*va.x + va.y*va.y + va.z*va.z + va.w*va.w
                + vb.x*vb.x + vb.y*vb.y + vb.z*vb.z + vb.w*vb.w;
            s16x8 f;
            f[0] = (short)f2bf(va.x); f[1] = (short)f2bf(va.y);
            f[2] = (short)f2bf(va.z); f[3] = (short)f2bf(va.w);
            f[4] = (short)f2bf(vb.x); f[5] = (short)f2bf(vb.y);
            f[6] = (short)f2bf(vb.z); f[7] = (short)f2bf(vb.w);
            pf[kk] = f;
            *(s16x8*)(pf_lds + (size_t)(w * 4 + kk) * 512 + l * 8) = f;
        }
        s  += __shfl_xor(s, 16);  ss += __shfl_xor(ss, 16);
        s  += __shfl_xor(s, 32);  ss += __shfl_xor(ss, 32);
        float mu = s * (1.f / 128.f), mq = ss * (1.f / 128.f);
        float rv  = rsqrtf(mq + 1.1920929e-07f);
        float var = mq - mu * mu;

        // routing mini-GEMM
        f32x4 y1 = {0.f, 0.f, 0.f, 0.f}, y2 = {0.f, 0.f, 0.f, 0.f};
        #pragma unroll
        for (int kk = 0; kk < 4; ++kk) {
            s16x8 a0 = *(const s16x8*)(g_wefff + ((size_t)(kk) * 64 + l) * 8);
            s16x8 a1 = *(const s16x8*)(g_wefff + ((size_t)(4 + kk) * 64 + l) * 8);
            y1 = MFMA16(a0, pf[kk], y1);
            y2 = MFMA16(a1, pf[kk], y2);
        }
        #pragma unroll
        for (int r = 0; r < 4; ++r) { y1[r] *= rv; y2[r] *= rv; }

        float apre = a_pre[0], apost = a_post[0], ares = a_res[0];

        float sp_loc = 0.f;
        #pragma unroll
        for (int r = 0; r < 4; ++r)
            sp_loc += fast_sig(apre * fast_tanh(y1[r]) + b_pre[r]);
        float sp = __shfl(sp_loc, pixl);

        float hp0 = 2.f * fast_sig(apost * fast_tanh(y1[0]) + b_post[0]);
        float hp1 = 2.f * fast_sig(apost * fast_tanh(y1[1]) + b_post[1]);
        float hp2 = 2.f * fast_sig(apost * fast_tanh(y1[2]) + b_post[2]);
        float hp3 = 2.f * fast_sig(apost * fast_tanh(y1[3]) + b_post[3]);

        int m = (g + 2) & 3;
        bool lo = g < 2;
        float M0 = __expf(ares * fast_tanh(lo ? y2[0] : y1[0]) + b_res[m * 4 + 0]);
        float M1 = __expf(ares * fast_tanh(lo ? y2[1] : y1[1]) + b_res[m * 4 + 1]);
        float M2 = __expf(ares * fast_tanh(lo ? y2[2] : y1[2]) + b_res[m * 4 + 2]);
        float M3 = __expf(ares * fast_tanh(lo ? y2[3] : y1[3]) + b_res[m * 4 + 3]);
        #pragma unroll 1
        for (int it = 0; it < 20; ++it) {
            float ri = __builtin_amdgcn_rcpf(M0 + M1 + M2 + M3);
            M0 *= ri; M1 *= ri; M2 *= ri; M3 *= ri;
            float c0 = M0, c1 = M1, c2 = M2, c3 = M3;
            c0 += __shfl_xor(c0, 16); c1 += __shfl_xor(c1, 16); c2 += __shfl_xor(c2, 16); c3 += __shfl_xor(c3, 16);
            c0 += __shfl_xor(c0, 32); c1 += __shfl_xor(c1, 32); c2 += __shfl_xor(c2, 32); c3 += __shfl_xor(c3, 32);
            M0 *= __builtin_amdgcn_rcpf(c0); M1 *= __builtin_amdgcn_rcpf(c1);
            M2 *= __builtin_amdgcn_rcpf(c2); M3 *= __builtin_amdgcn_rcpf(c3);
        }
        float rm = M0 + M1 + M2 + M3;

        float h0b = __shfl(hp0, pixl + 16);
        float h1b = __shfl(hp1, pixl + 16);
        float h2b = __shfl(hp2, pixl + 16);
        float h3b = __shfl(hp3, pixl + 16);
        float hpm = (m & 2) ? ((m & 1) ? h3b : h2b) : ((m & 1) ? h1b : h0b);

        float msk = p_mask[gpix];
        int pix = w * 16 + pixl;
        A_s[pix * 4 + m] = rm + hpm * sp;
        B_s[pix * 4 + m] = hpm * msk;
        if (l < 16) {
            float istd = rsqrtf(sp * sp * var + 1e-5f);
            simi_s[pix] = make_float2(sp * istd, sp * mu * istd);
        }
    }
    __syncthreads();   // B1: pf_lds + simi (and A/B) ready

    float2 sim0 = simi_s[lr];
    float2 sim1 = simi_s[16 + lr];

    f32x4 acc2[2] = {};   // GEMM2 accumulators, carried across both phases

    // ======== two MLP phases: GEMM1-half -> fold -> h_s(16KB) -> GEMM2-half ========
    auto mlp_phase = [&](int phase) {
        // GEMM1: each wave owns 32 j-rows of this half (tiles T, T+1)
        f32x4 acc1[2][2] = {};
        #pragma unroll
        for (int kk = 0; kk < 4; ++kk) {
            s16x8 b0 = *(const s16x8*)(pf_lds + (size_t)(kk) * 512 + l * 8);
            s16x8 b1 = *(const s16x8*)(pf_lds + (size_t)(4 + kk) * 512 + l * 8);
            #pragma unroll
            for (int jt = 0; jt < 2; ++jt) {
                int T = phase * 16 + w * 2 + jt;
                s16x8 a = *(const s16x8*)(g_w1gf + ((size_t)(T * 4 + kk) * 64 + l) * 8);
                acc1[jt][0] = MFMA16(a, b0, acc1[jt][0]);
                acc1[jt][1] = MFMA16(a, b1, acc1[jt][1]);
            }
        }
        // fold LN scalars + bias + relu -> bf16 h_s (this half)
        #pragma unroll
        for (int jt = 0; jt < 2; ++jt) {
            int jl = w * 32 + jt * 16 + lk * 4;       // col within half, < 256
            int j0 = phase * 256 + jl;                // true j
            float4 wg = *(const float4*)(g_w1gs + j0);
            float4 ha = *(const float4*)(g_hA + j0);
            #pragma unroll
            for (int it = 0; it < 2; ++it) {
                int i = it * 16 + lr;
                float si = it ? sim1.x : sim0.x;
                float mi = it ? sim1.y : sim0.y;
                f32x4 v = acc1[jt][it];
                float h0 = fmaxf(fmaf(si, v[0], fmaf(-mi, wg.x, ha.x)), 0.f);
                float h1 = fmaxf(fmaf(si, v[1], fmaf(-mi, wg.y, ha.y)), 0.f);
                float h2 = fmaxf(fmaf(si, v[2], fmaf(-mi, wg.z, ha.z)), 0.f);
                float h3 = fmaxf(fmaf(si, v[3], fmaf(-mi, wg.w, ha.w)), 0.f);
                uint2 uu;
                uu.x = pack2(h0, h1);
                uu.y = pack2(h2, h3);
                uint32_t off = (uint32_t)(i * 512 + jl * 2) ^ ((i & 7) << 5);
                *(uint2*)((char*)h_s + off) = uu;
            }
        }
        __syncthreads();   // h half ready
        // GEMM2 half: D[c,i] partial over this k-half, wave w owns channels w*16..
        #pragma unroll
        for (int kk = 0; kk < 8; ++kk) {
            int K = phase * 8 + kk;
            s16x8 a = *(const s16x8*)(g_w2f + ((size_t)(w * 16 + K) * 64 + l) * 8);
            s16x8 b0, b1;
            {
                uint32_t off = (uint32_t)(lr * 512 + kk * 64 + lk * 16) ^ ((lr & 7) << 5);
                b0 = *(const s16x8*)((const char*)h_s + off);
            }
            {
                int i = 16 + lr;
                uint32_t off = (uint32_t)(i * 512 + kk * 64 + lk * 16) ^ ((i & 7) << 5);
                b1 = *(const s16x8*)((const char*)h_s + off);
            }
            acc2[0] = MFMA16(a, b0, acc2[0]);
            acc2[1] = MFMA16(a, b1, acc2[1]);
        }
    };

    mlp_phase(0);
    __syncthreads();   // h half-1 fully consumed before overwrite
    mlp_phase(1);

    // ======== epilogue: out[i,m,c] = A_im * p[c] + B_im * (D + b2) ========
    const int c0 = w * 16 + lk * 4;
    float4 b2v = *(const float4*)(b2g + c0);
    #pragma unroll
    for (int it = 0; it < 2; ++it) {
        int i = it * 16 + lr;
        f32x4 Av = *(const f32x4*)(A_s + i * 4);
        f32x4 Bv = *(const f32x4*)(B_s + i * 4);
        const unsigned short* pe = pf_lds
            + ((size_t)(it * 4 + (w >> 1)) * 64 + ((w & 1) * 2 + (lk >> 1)) * 16 + lr) * 8
            + (lk & 1) * 4;
        uint2 pb = *(const uint2*)pe;
        float p0 = bf2f(pb.x & 0xffffu), p1 = __uint_as_float(pb.x & 0xffff0000u);
        float p2 = bf2f(pb.y & 0xffffu), p3 = __uint_as_float(pb.y & 0xffff0000u);
        float d0 = acc2[it][0] + b2v.x, d1 = acc2[it][1] + b2v.y;
        float d2 = acc2[it][2] + b2v.z, d3 = acc2[it][3] + b2v.w;
        float* og = out + (base + i) * 512 + c0;
        #pragma unroll
        for (int m = 0; m < 4; ++m) {
            f32x4 o;
            o[0] = Av[m] * p0 + Bv[m] * d0;
            o[1] = Av[m] * p1 + Bv[m] * d1;
            o[2] = Av[m] * p2 + Bv[m] * d2;
            o[3] = Av[m] * p3 + Bv[m] * d3;
            *(f32x4*)(og + m * 128) = o;
        }
    }
}

extern "C" void kernel_launch(void* const* d_in, const int* in_sizes, int n_in,
                              void* d_out, int out_size, void* d_ws, size_t ws_size,
                              hipStream_t stream) {
    const float* p      = (const float*)d_in[0];
    const float* p_mask = (const float*)d_in[1];
    const float* W_pre  = (const float*)d_in[2];
    const float* W_post = (const float*)d_in[3];
    const float* W_res  = (const float*)d_in[4];
    const float* b_pre  = (const float*)d_in[5];
    const float* b_post = (const float*)d_in[6];
    const float* b_res  = (const float*)d_in[7];
    const float* a_pre  = (const float*)d_in[8];
    const float* a_post = (const float*)d_in[9];
    const float* a_res  = (const float*)d_in[10];
    const float* ln_g   = (const float*)d_in[11];
    const float* ln_b   = (const float*)d_in[12];
    const float* W1     = (const float*)d_in[13];
    const float* b1     = (const float*)d_in[14];
    const float* W2     = (const float*)d_in[15];
    const float* b2     = (const float*)d_in[16];
    float* out = (float*)d_out;

    prep_kernel<<<265, 512, 0, stream>>>(W_pre, W_post, W_res, W1, W2, ln_g, ln_b, b1);
    fused_kernel<<<2048, 512, 0, stream>>>(p, p_mask, b_pre, b_post, b_res,
                                           a_pre, a_post, a_res, b2, out);
}

// Round 9
// 75.462 us; speedup vs baseline: 1.1598x; 1.1598x over previous
//
#include <hip/hip_runtime.h>
#include <stdint.h>

// Problem constants (B=1, L=256, C=128, N=4, TN=4)
#define LLTOT 65536
#define CDIM  128
#define TPIX  32

typedef float f32x4 __attribute__((ext_vector_type(4)));
typedef short s16x8 __attribute__((ext_vector_type(8)));

#define MFMA16(a, b, c) __builtin_amdgcn_mfma_f32_16x16x32_bf16((a), (b), (c), 0, 0, 0)

// ---- persistent device scratch (weights only) ----
// fragment-linear layouts: [tile][kk][lane 0..63][8 bf16]  (lane: row = l&15, k-chunk = l>>4)
__device__ __align__(16) unsigned short g_wefff[2 * 4 * 64 * 8];    // routing weights (rows 24-31 zero)
__device__ __align__(16) unsigned short g_w1gf[32 * 4 * 64 * 8];    // W1 * ln_g
__device__ __align__(16) unsigned short g_w2f [8 * 16 * 64 * 8];    // W2
__device__ __align__(16) float  g_hA[512];                          // b1 + W1 @ ln_b
__device__ __align__(16) float  g_w1gs[512];                        // row sums of W1*ln_g

__device__ __forceinline__ unsigned short f2bf(float f) {
    union { float f; uint32_t u; } v; v.f = f;
    uint32_t u = v.u;
    return (unsigned short)((u + 0x7FFFu + ((u >> 16) & 1u)) >> 16);
}
// single-instruction RNE pack of 2 f32 -> 2 bf16 (T12 recipe, gfx950-verified)
__device__ __forceinline__ uint32_t pack2(float a, float b) {
    uint32_t r;
    asm("v_cvt_pk_bf16_f32 %0, %1, %2" : "=v"(r) : "v"(a), "v"(b));
    return r;
}
__device__ __forceinline__ float bf2f(uint32_t lo16) { return __uint_as_float(lo16 << 16); }

__device__ __forceinline__ float fast_tanh(float x) {
    float cx = fminf(fmaxf(x, -10.f), 10.f);
    float e = __expf(2.f * cx);
    return (e - 1.f) * __builtin_amdgcn_rcpf(e + 1.f);
}
__device__ __forceinline__ float fast_sig(float z) {
    return __builtin_amdgcn_rcpf(1.f + __expf(-z));
}

// ---- prep: fold weights, convert to bf16, write fragment-linear layouts ----
__global__ void prep_kernel(const float* __restrict__ Wpre, const float* __restrict__ Wpost,
                            const float* __restrict__ Wres, const float* __restrict__ W1,
                            const float* __restrict__ W2, const float* __restrict__ ln_g,
                            const float* __restrict__ ln_b, const float* __restrict__ b1) {
    int b = blockIdx.x, t = threadIdx.x;
    if (b == 264) {
        int j = t;   // 512 threads
        float sg = 0.f, sb = 0.f;
        const float* row = W1 + j * 128;
        #pragma unroll 4
        for (int c = 0; c < 128; c += 4) {
            float4 wv = *(const float4*)(row + c);
            float4 gv = *(const float4*)(ln_g + c);
            float4 bv = *(const float4*)(ln_b + c);
            sg += wv.x*gv.x + wv.y*gv.y + wv.z*gv.z + wv.w*gv.w;
            sb += wv.x*bv.x + wv.y*bv.y + wv.z*bv.z + wv.w*bv.w;
        }
        g_hA[j]   = b1[j] + sb;
        g_w1gs[j] = sg;
        return;
    }
    int idx = b * 512 + t;
    if (idx < 4096) {
        // weff fragments: d -> (tile,kk,lane,e)
        int e = idx & 7, lane = (idx >> 3) & 63, kk = (idx >> 9) & 3, tile = idx >> 11;
        int o = tile * 16 + (lane & 15);
        int c = kk * 32 + (lane >> 4) * 8 + e;
        float v = 0.f;
        if (o < 4)        v = Wpre[o*512+c] + Wpre[o*512+128+c] + Wpre[o*512+256+c] + Wpre[o*512+384+c];
        else if (o < 8)   { int j = o - 4;  v = Wpost[j*512+c] + Wpost[j*512+128+c] + Wpost[j*512+256+c] + Wpost[j*512+384+c]; }
        else if (o < 24)  { int j = o - 8;  v = Wres[j*512+c] + Wres[j*512+128+c] + Wres[j*512+256+c] + Wres[j*512+384+c]; }
        g_wefff[idx] = f2bf(v);
    } else if (idx < 69632) {
        int d = idx - 4096;
        int e = d & 7, lane = (d >> 3) & 63, kk = (d >> 9) & 3, jt = d >> 11;
        int j = jt * 16 + (lane & 15);
        int c = kk * 32 + (lane >> 4) * 8 + e;
        g_w1gf[d] = f2bf(W1[j * 128 + c] * ln_g[c]);
    } else if (idx < 135168) {
        int d = idx - 69632;
        int e = d & 7, lane = (d >> 3) & 63, kk = (d >> 9) & 15, ct = d >> 13;
        int c = ct * 16 + (lane & 15);
        int k = kk * 32 + (lane >> 4) * 8 + e;
        g_w2f[d] = f2bf(W2[c * 512 + k]);
    }
}

// ---- fused: waves 0-1 route ; 2-phase MLP (16 KB h) ; 4 barriers ----
__global__ void __launch_bounds__(512, 4) fused_kernel(
    const float* __restrict__ p, const float* __restrict__ p_mask,
    const float* __restrict__ b_pre, const float* __restrict__ b_post, const float* __restrict__ b_res,
    const float* __restrict__ a_pre, const float* __restrict__ a_post, const float* __restrict__ a_res,
    const float* __restrict__ b2g, float* __restrict__ out)
{
    __shared__ __align__(16) unsigned short pf_lds[8 * 64 * 8];   // 8 KB bf16 p fragments
    __shared__ __align__(16) unsigned short h_s[TPIX * 256];      // 16 KB bf16 relu(h) HALF, row stride 512B, swz <<5
    __shared__ __align__(16) float A_s[TPIX * 4], B_s[TPIX * 4];  // 1 KB
    __shared__ __align__(16) float2 simi_s[TPIX];                 // 256 B

    const int t = threadIdx.x;
    const int w = t >> 6, l = t & 63, lr = l & 15, lk = l >> 4;
    const size_t base = (size_t)blockIdx.x * 32;

    // ======== waves 0-1: full route for this block's 32 pixels (no barriers inside) ========
    if (w < 2) {
        const int g = lk, pixl = lr;
        const size_t gpix = base + w * 16 + pixl;

        float s = 0.f, ss = 0.f;
        s16x8 pf[4];
        const float* prow = p + gpix * 128 + g * 8;
        #pragma unroll
        for (int kk = 0; kk < 4; ++kk) {
            float4 va = *(const float4*)(prow + kk * 32);
            float4 vb = *(const float4*)(prow + kk * 32 + 4);
            s  += va.x + va.y + va.z + va.w + vb.x + vb.y + vb.z + vb.w;
            ss += va.x*va.x + va.y*va.y + va.z*va.z + va.w*va.w
                + vb.x*vb.x + vb.y*vb.y + vb.z*vb.z + vb.w*vb.w;
            union { s16x8 v; uint32_t u[4]; } cc;
            cc.u[0] = pack2(va.x, va.y);
            cc.u[1] = pack2(va.z, va.w);
            cc.u[2] = pack2(vb.x, vb.y);
            cc.u[3] = pack2(vb.z, vb.w);
            pf[kk] = cc.v;
            *(s16x8*)(pf_lds + (size_t)(w * 4 + kk) * 512 + l * 8) = cc.v;
        }
        s  += __shfl_xor(s, 16);  ss += __shfl_xor(ss, 16);
        s  += __shfl_xor(s, 32);  ss += __shfl_xor(ss, 32);
        float mu = s * (1.f / 128.f), mq = ss * (1.f / 128.f);
        float rv  = rsqrtf(mq + 1.1920929e-07f);
        float var = mq - mu * mu;

        // routing mini-GEMM
        f32x4 y1 = {0.f, 0.f, 0.f, 0.f}, y2 = {0.f, 0.f, 0.f, 0.f};
        #pragma unroll
        for (int kk = 0; kk < 4; ++kk) {
            s16x8 a0 = *(const s16x8*)(g_wefff + ((size_t)(kk) * 64 + l) * 8);
            s16x8 a1 = *(const s16x8*)(g_wefff + ((size_t)(4 + kk) * 64 + l) * 8);
            y1 = MFMA16(a0, pf[kk], y1);
            y2 = MFMA16(a1, pf[kk], y2);
        }
        #pragma unroll
        for (int r = 0; r < 4; ++r) { y1[r] *= rv; y2[r] *= rv; }

        float apre = a_pre[0], apost = a_post[0], ares = a_res[0];

        float sp_loc = 0.f;
        #pragma unroll
        for (int r = 0; r < 4; ++r)
            sp_loc += fast_sig(apre * fast_tanh(y1[r]) + b_pre[r]);
        float sp = __shfl(sp_loc, pixl);

        float hp0 = 2.f * fast_sig(apost * fast_tanh(y1[0]) + b_post[0]);
        float hp1 = 2.f * fast_sig(apost * fast_tanh(y1[1]) + b_post[1]);
        float hp2 = 2.f * fast_sig(apost * fast_tanh(y1[2]) + b_post[2]);
        float hp3 = 2.f * fast_sig(apost * fast_tanh(y1[3]) + b_post[3]);

        int m = (g + 2) & 3;
        bool lo = g < 2;
        float M0 = __expf(ares * fast_tanh(lo ? y2[0] : y1[0]) + b_res[m * 4 + 0]);
        float M1 = __expf(ares * fast_tanh(lo ? y2[1] : y1[1]) + b_res[m * 4 + 1]);
        float M2 = __expf(ares * fast_tanh(lo ? y2[2] : y1[2]) + b_res[m * 4 + 2]);
        float M3 = __expf(ares * fast_tanh(lo ? y2[3] : y1[3]) + b_res[m * 4 + 3]);
        #pragma unroll 1
        for (int it = 0; it < 20; ++it) {
            float ri = __builtin_amdgcn_rcpf(M0 + M1 + M2 + M3);
            M0 *= ri; M1 *= ri; M2 *= ri; M3 *= ri;
            float c0 = M0, c1 = M1, c2 = M2, c3 = M3;
            c0 += __shfl_xor(c0, 16); c1 += __shfl_xor(c1, 16); c2 += __shfl_xor(c2, 16); c3 += __shfl_xor(c3, 16);
            c0 += __shfl_xor(c0, 32); c1 += __shfl_xor(c1, 32); c2 += __shfl_xor(c2, 32); c3 += __shfl_xor(c3, 32);
            M0 *= __builtin_amdgcn_rcpf(c0); M1 *= __builtin_amdgcn_rcpf(c1);
            M2 *= __builtin_amdgcn_rcpf(c2); M3 *= __builtin_amdgcn_rcpf(c3);
        }
        float rm = M0 + M1 + M2 + M3;

        float h0b = __shfl(hp0, pixl + 16);
        float h1b = __shfl(hp1, pixl + 16);
        float h2b = __shfl(hp2, pixl + 16);
        float h3b = __shfl(hp3, pixl + 16);
        float hpm = (m & 2) ? ((m & 1) ? h3b : h2b) : ((m & 1) ? h1b : h0b);

        float msk = p_mask[gpix];
        int pix = w * 16 + pixl;
        A_s[pix * 4 + m] = rm + hpm * sp;
        B_s[pix * 4 + m] = hpm * msk;
        if (l < 16) {
            float istd = rsqrtf(sp * sp * var + 1e-5f);
            simi_s[pix] = make_float2(sp * istd, sp * mu * istd);
        }
    }
    __syncthreads();   // B1: pf_lds + simi (and A/B) ready

    float2 sim0 = simi_s[lr];
    float2 sim1 = simi_s[16 + lr];

    f32x4 acc2[2] = {};   // GEMM2 accumulators, carried across both phases

    // ======== two MLP phases: GEMM1-half -> fold -> h_s(16KB) -> GEMM2-half ========
    auto mlp_phase = [&](int phase) {
        // GEMM1: each wave owns 32 j-rows of this half (tiles T, T+1)
        f32x4 acc1[2][2] = {};
        #pragma unroll
        for (int kk = 0; kk < 4; ++kk) {
            s16x8 b0 = *(const s16x8*)(pf_lds + (size_t)(kk) * 512 + l * 8);
            s16x8 b1 = *(const s16x8*)(pf_lds + (size_t)(4 + kk) * 512 + l * 8);
            #pragma unroll
            for (int jt = 0; jt < 2; ++jt) {
                int T = phase * 16 + w * 2 + jt;
                s16x8 a = *(const s16x8*)(g_w1gf + ((size_t)(T * 4 + kk) * 64 + l) * 8);
                acc1[jt][0] = MFMA16(a, b0, acc1[jt][0]);
                acc1[jt][1] = MFMA16(a, b1, acc1[jt][1]);
            }
        }
        // fold LN scalars + bias + relu -> bf16 h_s (this half)
        #pragma unroll
        for (int jt = 0; jt < 2; ++jt) {
            int jl = w * 32 + jt * 16 + lk * 4;       // col within half, < 256
            int j0 = phase * 256 + jl;                // true j
            float4 wg = *(const float4*)(g_w1gs + j0);
            float4 ha = *(const float4*)(g_hA + j0);
            #pragma unroll
            for (int it = 0; it < 2; ++it) {
                int i = it * 16 + lr;
                float si = it ? sim1.x : sim0.x;
                float mi = it ? sim1.y : sim0.y;
                f32x4 v = acc1[jt][it];
                float h0 = fmaxf(fmaf(si, v[0], fmaf(-mi, wg.x, ha.x)), 0.f);
                float h1 = fmaxf(fmaf(si, v[1], fmaf(-mi, wg.y, ha.y)), 0.f);
                float h2 = fmaxf(fmaf(si, v[2], fmaf(-mi, wg.z, ha.z)), 0.f);
                float h3 = fmaxf(fmaf(si, v[3], fmaf(-mi, wg.w, ha.w)), 0.f);
                uint2 uu;
                uu.x = pack2(h0, h1);
                uu.y = pack2(h2, h3);
                uint32_t off = (uint32_t)(i * 512 + jl * 2) ^ ((i & 7) << 5);
                *(uint2*)((char*)h_s + off) = uu;
            }
        }
        __syncthreads();   // h half ready
        // GEMM2 half: D[c,i] partial over this k-half, wave w owns channels w*16..
        #pragma unroll
        for (int kk = 0; kk < 8; ++kk) {
            int K = phase * 8 + kk;
            s16x8 a = *(const s16x8*)(g_w2f + ((size_t)(w * 16 + K) * 64 + l) * 8);
            s16x8 b0, b1;
            {
                uint32_t off = (uint32_t)(lr * 512 + kk * 64 + lk * 16) ^ ((lr & 7) << 5);
                b0 = *(const s16x8*)((const char*)h_s + off);
            }
            {
                int i = 16 + lr;
                uint32_t off = (uint32_t)(i * 512 + kk * 64 + lk * 16) ^ ((i & 7) << 5);
                b1 = *(const s16x8*)((const char*)h_s + off);
            }
            acc2[0] = MFMA16(a, b0, acc2[0]);
            acc2[1] = MFMA16(a, b1, acc2[1]);
        }
    };

    mlp_phase(0);
    __syncthreads();   // h half-1 fully consumed before overwrite
    mlp_phase(1);

    // ======== epilogue: out[i,m,c] = A_im * p[c] + B_im * (D + b2) ========
    const int c0 = w * 16 + lk * 4;
    float4 b2v = *(const float4*)(b2g + c0);
    #pragma unroll
    for (int it = 0; it < 2; ++it) {
        int i = it * 16 + lr;
        f32x4 Av = *(const f32x4*)(A_s + i * 4);
        f32x4 Bv = *(const f32x4*)(B_s + i * 4);
        const unsigned short* pe = pf_lds
            + ((size_t)(it * 4 + (w >> 1)) * 64 + ((w & 1) * 2 + (lk >> 1)) * 16 + lr) * 8
            + (lk & 1) * 4;
        uint2 pb = *(const uint2*)pe;
        float p0 = bf2f(pb.x & 0xffffu), p1 = __uint_as_float(pb.x & 0xffff0000u);
        float p2 = bf2f(pb.y & 0xffffu), p3 = __uint_as_float(pb.y & 0xffff0000u);
        float d0 = acc2[it][0] + b2v.x, d1 = acc2[it][1] + b2v.y;
        float d2 = acc2[it][2] + b2v.z, d3 = acc2[it][3] + b2v.w;
        float* og = out + (base + i) * 512 + c0;
        #pragma unroll
        for (int m = 0; m < 4; ++m) {
            f32x4 o;
            o[0] = Av[m] * p0 + Bv[m] * d0;
            o[1] = Av[m] * p1 + Bv[m] * d1;
            o[2] = Av[m] * p2 + Bv[m] * d2;
            o[3] = Av[m] * p3 + Bv[m] * d3;
            *(f32x4*)(og + m * 128) = o;
        }
    }
}

extern "C" void kernel_launch(void* const* d_in, const int* in_sizes, int n_in,
                              void* d_out, int out_size, void* d_ws, size_t ws_size,
                              hipStream_t stream) {
    const float* p      = (const float*)d_in[0];
    const float* p_mask = (const float*)d_in[1];
    const float* W_pre  = (const float*)d_in[2];
    const float* W_post = (const float*)d_in[3];
    const float* W_res  = (const float*)d_in[4];
    const float* b_pre  = (const float*)d_in[5];
    const float* b_post = (const float*)d_in[6];
    const float* b_res  = (const float*)d_in[7];
    const float* a_pre  = (const float*)d_in[8];
    const float* a_post = (const float*)d_in[9];
    const float* a_res  = (const float*)d_in[10];
    const float* ln_g   = (const float*)d_in[11];
    const float* ln_b   = (const float*)d_in[12];
    const float* W1     = (const float*)d_in[13];
    const float* b1     = (const float*)d_in[14];
    const float* W2     = (const float*)d_in[15];
    const float* b2     = (const float*)d_in[16];
    float* out = (float*)d_out;

    prep_kernel<<<265, 512, 0, stream>>>(W_pre, W_post, W_res, W1, W2, ln_g, ln_b, b1);
    fused_kernel<<<2048, 512, 0, stream>>>(p, p_mask, b_pre, b_post, b_res,
                                           a_pre, a_post, a_res, b2, out);
}